// Round 3
// baseline (1505.879 us; speedup 1.0000x reference)
//
#include <hip/hip_runtime.h>
#include <hip/hip_bf16.h>
#include <stdint.h>

#define NN 50000   // nodes
#define DI 128     // input features
#define DO 64      // output features
#define NE 800000  // edges per relation
#define NR 4       // relations
#define NB 782     // ceil(NN/64) 64-row blocks
#define NBUCK (NR*NB)   // 3128 buckets total
#define PCHUNK 7168     // edges per place workgroup
#define PWG ((NE + PCHUNK - 1) / PCHUNK)   // 112 per relation

// ---------------------------------------------------------------------------
// Block-wide exclusive scan of a[0..N) in LDS. BLK threads, PER elems/thread.
// Caller must __syncthreads() before and after.
// ---------------------------------------------------------------------------
template<int N, int PER, int BLK>
__device__ inline void block_exscan(int* a)
{
    __shared__ int wsum[BLK / 64];
    int tid = threadIdx.x;
    int base = tid * PER;
    int v[PER]; int s = 0;
    #pragma unroll
    for (int j = 0; j < PER; ++j) {
        int idx = base + j;
        int x = (idx < N) ? a[idx] : 0;
        v[j] = s; s += x;
    }
    int lane = tid & 63, wv = tid >> 6;
    int inc = s;
    #pragma unroll
    for (int off = 1; off < 64; off <<= 1) {
        int u = __shfl_up(inc, off);
        if (lane >= off) inc += u;
    }
    if (lane == 63) wsum[wv] = inc;
    __syncthreads();
    int woff = 0;
    for (int w = 0; w < wv; ++w) woff += wsum[w];
    int tb = woff + inc - s;
    #pragma unroll
    for (int j = 0; j < PER; ++j) {
        int idx = base + j;
        if (idx < N) a[idx] = tb + v[j];
    }
}

// ---------------------------------------------------------------------------
// GEMM: xw[r] = x @ W_r -> bf16 [NN, DO]. blockIdx.y = relation.
// ---------------------------------------------------------------------------
__global__ __launch_bounds__(256) void gemm_kernel(
    const float* __restrict__ x, const float* __restrict__ W,
    __hip_bfloat16* __restrict__ xwb)
{
    int r = blockIdx.y;
    const float* Wr = W + (size_t)r * DI * DO;
    __hip_bfloat16* xwr = xwb + (size_t)r * NN * DO;

    __shared__ float Wl[DI * DO];
    for (int i = threadIdx.x; i < DI * DO; i += 256) Wl[i] = Wr[i];
    __syncthreads();

    int wv   = __builtin_amdgcn_readfirstlane((int)(threadIdx.x >> 6));
    int lane = threadIdx.x & 63;
    int n0   = blockIdx.x * 32 + wv * 8;
    if (n0 >= NN) return;
    int nrows = NN - n0; if (nrows > 8) nrows = 8;

    if (nrows == 8) {
        const float* xr = x + (size_t)n0 * DI;
        float acc[8] = {0.f,0.f,0.f,0.f,0.f,0.f,0.f,0.f};
        #pragma unroll 8
        for (int k = 0; k < DI; ++k) {
            float w = Wl[k * DO + lane];
            #pragma unroll
            for (int rr = 0; rr < 8; ++rr)
                acc[rr] = fmaf(xr[(size_t)rr * DI + k], w, acc[rr]);
        }
        #pragma unroll
        for (int rr = 0; rr < 8; ++rr)
            xwr[(size_t)(n0 + rr) * DO + lane] = __float2bfloat16(acc[rr]);
    } else {
        for (int rr = 0; rr < nrows; ++rr) {
            const float* xr = x + (size_t)(n0 + rr) * DI;
            float acc = 0.f;
            for (int k = 0; k < DI; ++k)
                acc = fmaf(xr[k], Wl[k * DO + lane], acc);
            xwr[(size_t)(n0 + rr) * DO + lane] = __float2bfloat16(acc);
        }
    }
}

// ---------------------------------------------------------------------------
// Bucket histogram: gtot[r*NB + row>>6] += 1, LDS-aggregated.
// grid (32, NR): flush atomics = 128 * 782 = 100K (vs 3.2M per-row).
// ---------------------------------------------------------------------------
__global__ __launch_bounds__(256) void bhist_kernel(
    const int* __restrict__ rows, int* __restrict__ gtot)
{
    __shared__ int h[NB];
    int r = blockIdx.y;
    int tid = threadIdx.x;
    for (int i = tid; i < NB; i += 256) h[i] = 0;
    __syncthreads();
    const int* rr = rows + (size_t)r * NE;
    for (int k = blockIdx.x * 256 + tid; k < NE; k += gridDim.x * 256)
        atomicAdd(&h[rr[k] >> 6], 1);
    __syncthreads();
    int* gt = gtot + r * NB;
    for (int i = tid; i < NB; i += 256)
        if (h[i]) atomicAdd(&gt[i], h[i]);
}

// ---------------------------------------------------------------------------
// Scan bucket totals -> gstart[0..NBUCK] (bases, +total at end), gcur = copy.
// ---------------------------------------------------------------------------
__global__ __launch_bounds__(512) void bases_kernel(
    const int* __restrict__ gtot, int* __restrict__ gstart,
    int* __restrict__ gcur)
{
    __shared__ int a[NBUCK + 1];
    int tid = threadIdx.x;
    for (int i = tid; i < NBUCK + 1; i += 512) a[i] = (i < NBUCK) ? gtot[i] : 0;
    __syncthreads();
    block_exscan<NBUCK + 1, 7, 512>(a);
    __syncthreads();
    for (int i = tid; i < NBUCK + 1; i += 512) {
        gstart[i] = a[i];
        if (i < NBUCK) gcur[i] = a[i];
    }
}

// ---------------------------------------------------------------------------
// Placement: per wg, counting-sort a PCHUNK edge chunk by bucket in LDS,
// reserve contiguous global ranges (1 atomic per touched bucket), flush
// bucket-runs coalesced. Record: (col | rowlow<<16, val_bits).
// grid (PWG, NR). LDS = 3132 + 3128 + 57344 = 63.6KB.
// ---------------------------------------------------------------------------
__global__ __launch_bounds__(512) void place_kernel(
    const int* __restrict__ rows, const int* __restrict__ cols,
    const float* __restrict__ vals, int* __restrict__ gcur,
    int2* __restrict__ csr)
{
    __shared__ int lofs[NB + 1];
    __shared__ int gbase[NB];
    __shared__ int2 stag[PCHUNK];
    int r = blockIdx.y;
    int tid = threadIdx.x;
    int e0 = blockIdx.x * PCHUNK;
    int cnt = NE - e0; if (cnt > PCHUNK) cnt = PCHUNK;
    const int*   rr = rows + (size_t)r * NE + e0;
    const int*   cc = cols + (size_t)r * NE + e0;
    const float* vv = vals + (size_t)r * NE + e0;

    for (int i = tid; i <= NB; i += 512) lofs[i] = 0;
    __syncthreads();
    // pass 1: local bucket counts
    for (int k = tid; k < cnt; k += 512) atomicAdd(&lofs[rr[k] >> 6], 1);
    __syncthreads();
    block_exscan<NB + 1, 2, 512>(lofs);   // lofs[b] = local start of bucket b
    __syncthreads();
    // reserve global ranges (one atomic per nonzero bucket)
    for (int b = tid; b < NB; b += 512) {
        int c = lofs[b + 1] - lofs[b];
        if (c > 0) gbase[b] = atomicAdd(&gcur[r * NB + b], c);
    }
    __syncthreads();
    // pass 2: stage bucket-sorted into LDS (lofs becomes running cursor;
    // final lofs[b] == original lofs[b+1], i.e. end of run b)
    for (int k = tid; k < cnt; k += 512) {
        int row = rr[k];
        int b = row >> 6;
        int slot = atomicAdd(&lofs[b], 1);
        stag[slot] = make_int2((cc[k] & 0xFFFF) | ((row & 63) << 16),
                               __float_as_int(vv[k]));
    }
    __syncthreads();
    // pass 3: coalesced flush; bucket(i) = first b with lofs[b] > i
    for (int i = tid; i < cnt; i += 512) {
        int lo = 0, hi = NB - 1;
        while (lo < hi) {
            int mid = (lo + hi) >> 1;
            if (lofs[mid] > i) hi = mid; else lo = mid + 1;
        }
        int start = lo ? lofs[lo - 1] : 0;
        csr[gbase[lo] + (i - start)] = stag[i];
    }
}

// ---------------------------------------------------------------------------
// Fused SpMM: one wg per 64-row block. Per relation: stream that block's
// contiguous edge run, gather bf16 features, ds_add_f32 into LDS tile;
// then relu+bias accumulate. Epilogue: L2 normalize + store.
// Half-wave per edge: lanes l2 handle features l2 and l2+32 (bank-clean).
// ---------------------------------------------------------------------------
__global__ __launch_bounds__(256) void spmm_kernel(
    const uint16_t* __restrict__ xw16, const int2* __restrict__ csr,
    const int* __restrict__ gstart, const float* __restrict__ bias,
    float* __restrict__ out)
{
    __shared__ float agg[64 * 64];
    __shared__ float acc[64 * 64];
    int tid = threadIdx.x;
    int blk = blockIdx.x;
    for (int i = tid; i < 4096; i += 256) { agg[i] = 0.f; acc[i] = 0.f; }
    __syncthreads();
    int lane = tid & 63, wv = tid >> 6;
    int l2 = lane & 31, half = lane >> 5;

    for (int r = 0; r < NR; ++r) {
        int b = r * NB + blk;
        int s = gstart[b], e = gstart[b + 1];
        #pragma unroll 4
        for (int i0 = s + 2 * wv; i0 < e; i0 += 8) {
            int idx = i0 + half;
            int2 cv = (idx < e) ? csr[idx] : make_int2(0, 0);
            int col = cv.x & 0xFFFF;
            int rl  = (cv.x >> 16) & 63;
            float v = __int_as_float(cv.y);
            const uint16_t* p = xw16 + (((size_t)r * NN + col) << 6) + l2;
            float f0 = __uint_as_float(((uint32_t)p[0])  << 16);
            float f1 = __uint_as_float(((uint32_t)p[32]) << 16);
            atomicAdd(&agg[rl * 64 + l2],      v * f0);
            atomicAdd(&agg[rl * 64 + 32 + l2], v * f1);
        }
        __syncthreads();
        for (int i = tid; i < 4096; i += 256) {
            acc[i] += fmaxf(agg[i] + bias[r * DO + (i & 63)], 0.f);
            agg[i] = 0.f;
        }
        __syncthreads();
    }
    for (int row = wv; row < 64; row += 4) {
        int n = blk * 64 + row;
        if (n >= NN) break;
        float t = acc[row * 64 + lane];
        float s2 = t * t;
        #pragma unroll
        for (int off = 32; off >= 1; off >>= 1) s2 += __shfl_xor(s2, off);
        out[(size_t)n * DO + lane] = t / fmaxf(sqrtf(s2), 1e-12f);
    }
}

// ---------------------------------------------------------------------------
// Fallback path (small ws): R1 atomic-scatter pipeline.
// ---------------------------------------------------------------------------
__global__ __launch_bounds__(256) void scatter_kernel(
    const __hip_bfloat16* __restrict__ xwb, const float* __restrict__ vals,
    const int* __restrict__ rows, const int* __restrict__ cols,
    float* __restrict__ agg)
{
    const int nPairs = NE / 2;
    int gwave  = (blockIdx.x * 256 + threadIdx.x) >> 6;
    int half   = (threadIdx.x >> 5) & 1;
    int l32    = threadIdx.x & 31;
    int stride = gridDim.x * 4;
    const uint16_t* xw16 = reinterpret_cast<const uint16_t*>(xwb);
    for (int p = gwave; p < nPairs; p += stride) {
        int e = 2 * p + half;
        int row = rows[e]; int col = cols[e]; float v = vals[e];
        uint32_t packed = *reinterpret_cast<const uint32_t*>(
            xw16 + ((size_t)col << 6) + 2 * l32);
        float f0 = __uint_as_float(packed << 16);
        float f1 = __uint_as_float(packed & 0xFFFF0000u);
        float* dst = agg + ((size_t)row << 6) + 2 * l32;
        atomicAdd(dst,     v * f0);
        atomicAdd(dst + 1, v * f1);
    }
}

__global__ __launch_bounds__(256) void accum_kernel(
    float* __restrict__ agg, const float* __restrict__ b,
    float* __restrict__ out, int first)
{
    int i = blockIdx.x * 256 + threadIdx.x;
    if (i >= NN * DO) return;
    float v = agg[i] + b[i & (DO - 1)];
    agg[i] = 0.f;
    v = fmaxf(v, 0.f);
    out[i] = first ? v : (out[i] + v);
}

__global__ __launch_bounds__(256) void norm_kernel(float* __restrict__ out)
{
    int n = (blockIdx.x * 256 + threadIdx.x) >> 6;
    int lane = threadIdx.x & 63;
    if (n >= NN) return;
    size_t idx = (size_t)n * DO + lane;
    float t = out[idx];
    float s = t * t;
    #pragma unroll
    for (int off = 32; off >= 1; off >>= 1) s += __shfl_xor(s, off);
    out[idx] = t / fmaxf(sqrtf(s), 1e-12f);
}

extern "C" void kernel_launch(void* const* d_in, const int* in_sizes, int n_in,
                              void* d_out, int out_size, void* d_ws, size_t ws_size,
                              hipStream_t stream)
{
    const float* x    = (const float*)d_in[0];
    const float* W    = (const float*)d_in[1];
    const float* b    = (const float*)d_in[2];
    const float* vals = (const float*)d_in[3];
    const int*   rows = (const int*)d_in[4];
    const int*   cols = (const int*)d_in[5];
    float* out = (float*)d_out;
    char* ws = (char*)d_ws;

    // ws layout: xwb 25.6MB | csr 25.6MB | gtot | gstart | gcur  = 51.24MB
    const size_t O_XW = 0;
    const size_t O_CS = O_XW + (size_t)NR * NN * DO * 2;
    const size_t O_GT = O_CS + (size_t)NR * NE * 8;
    const size_t O_GS = O_GT + (size_t)NBUCK * 4;
    const size_t O_GC = O_GS + (size_t)(NBUCK + 1) * 4;
    const size_t NEED = O_GC + (size_t)NBUCK * 4;

    if (ws_size >= NEED) {
        __hip_bfloat16* xwb = (__hip_bfloat16*)(ws + O_XW);
        int2* csr   = (int2*)(ws + O_CS);
        int* gtot   = (int*)(ws + O_GT);
        int* gstart = (int*)(ws + O_GS);
        int* gcur   = (int*)(ws + O_GC);

        hipMemsetAsync(gtot, 0, (size_t)NBUCK * 4, stream);
        gemm_kernel<<<dim3((NN + 31) / 32, NR), dim3(256), 0, stream>>>(x, W, xwb);
        bhist_kernel<<<dim3(32, NR), dim3(256), 0, stream>>>(rows, gtot);
        bases_kernel<<<dim3(1), dim3(512), 0, stream>>>(gtot, gstart, gcur);
        place_kernel<<<dim3(PWG, NR), dim3(512), 0, stream>>>(rows, cols, vals, gcur, csr);
        spmm_kernel<<<dim3(NB), dim3(256), 0, stream>>>(
            (const uint16_t*)xwb, csr, gstart, b, out);
    } else {
        // sequential atomic-scatter fallback (19.2MB)
        __hip_bfloat16* xwb = (__hip_bfloat16*)ws;
        float* agg = (float*)(ws + (size_t)NN * DO * 2);
        hipMemsetAsync(agg, 0, (size_t)NN * DO * 4, stream);
        for (int r = 0; r < NR; ++r) {
            gemm_kernel<<<dim3((NN + 31) / 32, 1), dim3(256), 0, stream>>>(
                x, W + (size_t)r * DI * DO, xwb);
            scatter_kernel<<<dim3(2048), dim3(256), 0, stream>>>(
                xwb, vals + (size_t)r * NE, rows + (size_t)r * NE,
                cols + (size_t)r * NE, agg);
            accum_kernel<<<dim3((NN * DO + 255) / 256), dim3(256), 0, stream>>>(
                agg, b + (size_t)r * DO, out, r == 0);
        }
        norm_kernel<<<dim3((NN * DO + 255) / 256), dim3(256), 0, stream>>>(out);
    }
}

// Round 4
// 374.396 us; speedup vs baseline: 4.0222x; 4.0222x over previous
//
#include <hip/hip_runtime.h>
#include <hip/hip_bf16.h>
#include <stdint.h>

#define NN 50000   // nodes
#define DI 128     // input features
#define DO 64      // output features
#define NE 800000  // edges per relation
#define NR 4       // relations
#define NB 782     // ceil(NN/64) 64-row blocks
#define NBUCK (NR*NB)   // 3128 buckets total
#define PCHUNK 7168     // edges per place workgroup
#define PWG ((NE + PCHUNK - 1) / PCHUNK)   // 112 per relation
#define RSCAP 4096      // rowsort bucket capacity (mean 1023, cap = mean+96sigma)

// ---------------------------------------------------------------------------
// Block-wide exclusive scan of a[0..N) in LDS. BLK threads, PER elems/thread.
// ---------------------------------------------------------------------------
template<int N, int PER, int BLK>
__device__ inline void block_exscan(int* a)
{
    __shared__ int wsum[BLK / 64];
    int tid = threadIdx.x;
    int base = tid * PER;
    int v[PER]; int s = 0;
    #pragma unroll
    for (int j = 0; j < PER; ++j) {
        int idx = base + j;
        int x = (idx < N) ? a[idx] : 0;
        v[j] = s; s += x;
    }
    int lane = tid & 63, wv = tid >> 6;
    int inc = s;
    #pragma unroll
    for (int off = 1; off < 64; off <<= 1) {
        int u = __shfl_up(inc, off);
        if (lane >= off) inc += u;
    }
    if (lane == 63) wsum[wv] = inc;
    __syncthreads();
    int woff = 0;
    for (int w = 0; w < wv; ++w) woff += wsum[w];
    int tb = woff + inc - s;
    #pragma unroll
    for (int j = 0; j < PER; ++j) {
        int idx = base + j;
        if (idx < N) a[idx] = tb + v[j];
    }
}

// ---------------------------------------------------------------------------
// GEMM: xw[r] = x @ W_r -> bf16 [NN, DO]. blockIdx.y = relation.
// ---------------------------------------------------------------------------
__global__ __launch_bounds__(256) void gemm_kernel(
    const float* __restrict__ x, const float* __restrict__ W,
    __hip_bfloat16* __restrict__ xwb)
{
    int r = blockIdx.y;
    const float* Wr = W + (size_t)r * DI * DO;
    __hip_bfloat16* xwr = xwb + (size_t)r * NN * DO;

    __shared__ float Wl[DI * DO];
    for (int i = threadIdx.x; i < DI * DO; i += 256) Wl[i] = Wr[i];
    __syncthreads();

    int wv   = __builtin_amdgcn_readfirstlane((int)(threadIdx.x >> 6));
    int lane = threadIdx.x & 63;
    int n0   = blockIdx.x * 32 + wv * 8;
    if (n0 >= NN) return;
    int nrows = NN - n0; if (nrows > 8) nrows = 8;

    if (nrows == 8) {
        const float* xr = x + (size_t)n0 * DI;
        float acc[8] = {0.f,0.f,0.f,0.f,0.f,0.f,0.f,0.f};
        #pragma unroll 8
        for (int k = 0; k < DI; ++k) {
            float w = Wl[k * DO + lane];
            #pragma unroll
            for (int rr = 0; rr < 8; ++rr)
                acc[rr] = fmaf(xr[(size_t)rr * DI + k], w, acc[rr]);
        }
        #pragma unroll
        for (int rr = 0; rr < 8; ++rr)
            xwr[(size_t)(n0 + rr) * DO + lane] = __float2bfloat16(acc[rr]);
    } else {
        for (int rr = 0; rr < nrows; ++rr) {
            const float* xr = x + (size_t)(n0 + rr) * DI;
            float acc = 0.f;
            for (int k = 0; k < DI; ++k)
                acc = fmaf(xr[k], Wl[k * DO + lane], acc);
            xwr[(size_t)(n0 + rr) * DO + lane] = __float2bfloat16(acc);
        }
    }
}

// ---------------------------------------------------------------------------
// Bucket histogram: gtot[r*NB + row>>6] += 1, LDS-aggregated.
// ---------------------------------------------------------------------------
__global__ __launch_bounds__(256) void bhist_kernel(
    const int* __restrict__ rows, int* __restrict__ gtot)
{
    __shared__ int h[NB];
    int r = blockIdx.y;
    int tid = threadIdx.x;
    for (int i = tid; i < NB; i += 256) h[i] = 0;
    __syncthreads();
    const int* rr = rows + (size_t)r * NE;
    for (int k = blockIdx.x * 256 + tid; k < NE; k += gridDim.x * 256)
        atomicAdd(&h[rr[k] >> 6], 1);
    __syncthreads();
    int* gt = gtot + r * NB;
    for (int i = tid; i < NB; i += 256)
        if (h[i]) atomicAdd(&gt[i], h[i]);
}

// ---------------------------------------------------------------------------
// Scan bucket totals -> gstart[0..NBUCK] + gcur copy.
// ---------------------------------------------------------------------------
__global__ __launch_bounds__(512) void bases_kernel(
    const int* __restrict__ gtot, int* __restrict__ gstart,
    int* __restrict__ gcur)
{
    __shared__ int a[NBUCK + 1];
    int tid = threadIdx.x;
    for (int i = tid; i < NBUCK + 1; i += 512) a[i] = (i < NBUCK) ? gtot[i] : 0;
    __syncthreads();
    block_exscan<NBUCK + 1, 7, 512>(a);
    __syncthreads();
    for (int i = tid; i < NBUCK + 1; i += 512) {
        gstart[i] = a[i];
        if (i < NBUCK) gcur[i] = a[i];
    }
}

// ---------------------------------------------------------------------------
// Placement: counting-sort a PCHUNK edge chunk by 64-row bucket in LDS,
// reserve global ranges, flush coalesced. Record: (col | rowlow<<16, val).
// ---------------------------------------------------------------------------
__global__ __launch_bounds__(512) void place_kernel(
    const int* __restrict__ rows, const int* __restrict__ cols,
    const float* __restrict__ vals, int* __restrict__ gcur,
    int2* __restrict__ csr)
{
    __shared__ int lofs[NB + 1];
    __shared__ int gbase[NB];
    __shared__ int2 stag[PCHUNK];
    int r = blockIdx.y;
    int tid = threadIdx.x;
    int e0 = blockIdx.x * PCHUNK;
    int cnt = NE - e0; if (cnt > PCHUNK) cnt = PCHUNK;
    const int*   rr = rows + (size_t)r * NE + e0;
    const int*   cc = cols + (size_t)r * NE + e0;
    const float* vv = vals + (size_t)r * NE + e0;

    for (int i = tid; i <= NB; i += 512) lofs[i] = 0;
    __syncthreads();
    for (int k = tid; k < cnt; k += 512) atomicAdd(&lofs[rr[k] >> 6], 1);
    __syncthreads();
    block_exscan<NB + 1, 2, 512>(lofs);
    __syncthreads();
    for (int b = tid; b < NB; b += 512) {
        int c = lofs[b + 1] - lofs[b];
        if (c > 0) gbase[b] = atomicAdd(&gcur[r * NB + b], c);
    }
    __syncthreads();
    for (int k = tid; k < cnt; k += 512) {
        int row = rr[k];
        int b = row >> 6;
        int slot = atomicAdd(&lofs[b], 1);
        stag[slot] = make_int2((cc[k] & 0xFFFF) | ((row & 63) << 16),
                               __float_as_int(vv[k]));
    }
    __syncthreads();
    for (int i = tid; i < cnt; i += 512) {
        int lo = 0, hi = NB - 1;
        while (lo < hi) {
            int mid = (lo + hi) >> 1;
            if (lofs[mid] > i) hi = mid; else lo = mid + 1;
        }
        int start = lo ? lofs[lo - 1] : 0;
        csr[gbase[lo] + (i - start)] = stag[i];
    }
}

// ---------------------------------------------------------------------------
// Within-bucket counting sort by row (in place) + emit per-row rowptr.
// One wg per (bucket, relation). Edges -> regs (static idx), 64-bin count,
// wave-exscan, LDS scatter, coalesced write-back.
// ---------------------------------------------------------------------------
__global__ __launch_bounds__(256) void rowsort_kernel(
    int2* __restrict__ csr, const int* __restrict__ gstart,
    int* __restrict__ rowptr)
{
    __shared__ int2 stag[RSCAP];
    __shared__ int cnt[64];
    __shared__ int ofs[64];
    int blk = blockIdx.x;
    int r   = blockIdx.y;
    int b   = r * NB + blk;
    int s = gstart[b], e = gstart[b + 1];
    int cntE = e - s; if (cntE > RSCAP) cntE = RSCAP;
    int tid = threadIdx.x;
    if (tid < 64) cnt[tid] = 0;
    __syncthreads();

    int2 ed[RSCAP / 256];
    #pragma unroll
    for (int j = 0; j < RSCAP / 256; ++j) {
        int i = tid + j * 256;
        if (i < cntE) {
            ed[j] = csr[s + i];
            atomicAdd(&cnt[(ed[j].x >> 16) & 63], 1);
        }
    }
    __syncthreads();
    if (tid < 64) {
        int c = cnt[tid];
        int inc = c;
        #pragma unroll
        for (int off = 1; off < 64; off <<= 1) {
            int u = __shfl_up(inc, off);
            if (tid >= off) inc += u;
        }
        ofs[tid] = inc - c;                 // exclusive prefix
        int n = blk * 64 + tid;
        if (n < NN) rowptr[(size_t)r * NN + n] = s + inc - c;
        if (b == NBUCK - 1 && tid == 0)
            rowptr[(size_t)NR * NN] = gstart[NBUCK];
    }
    __syncthreads();
    #pragma unroll
    for (int j = 0; j < RSCAP / 256; ++j) {
        int i = tid + j * 256;
        if (i < cntE) {
            int rl = (ed[j].x >> 16) & 63;
            int slot = atomicAdd(&ofs[rl], 1);
            stag[slot] = ed[j];
        }
    }
    __syncthreads();
    for (int i = tid; i < cntE; i += 256) csr[s + i] = stag[i];
}

// ---------------------------------------------------------------------------
// Fused SpMM over 4 relations + bias + relu + sum + L2 normalize.
// One wave per node row, lane = feature, 4 relation chains interleaved.
// ---------------------------------------------------------------------------
__global__ __launch_bounds__(256) void spmm_fused_kernel(
    const uint16_t* __restrict__ xw16, const int2* __restrict__ csr,
    const int* __restrict__ rowptr, const float* __restrict__ b,
    float* __restrict__ out)
{
    int n = __builtin_amdgcn_readfirstlane(
        (int)((blockIdx.x * 256 + threadIdx.x) >> 6));
    int lane = threadIdx.x & 63;
    if (n >= NN) return;

    int si[NR], ei[NR];
    #pragma unroll
    for (int r = 0; r < NR; ++r) {
        si[r] = rowptr[(size_t)r * NN + n];
        ei[r] = rowptr[(size_t)r * NN + n + 1];
    }
    float acc[NR] = {0.f, 0.f, 0.f, 0.f};
    bool any = true;
    while (any) {
        any = false;
        #pragma unroll
        for (int r = 0; r < NR; ++r) {
            if (si[r] < ei[r]) {
                int2 cv = csr[si[r]];
                si[r] += 1;
                int col = cv.x & 0xFFFF;
                uint32_t u = xw16[(((size_t)r * NN + col) << 6) + lane];
                acc[r] = fmaf(__int_as_float(cv.y),
                              __uint_as_float(u << 16), acc[r]);
                any = true;
            }
        }
    }
    float total = 0.f;
    #pragma unroll
    for (int r = 0; r < NR; ++r)
        total += fmaxf(acc[r] + b[r * DO + lane], 0.f);
    float s2 = total * total;
    #pragma unroll
    for (int off = 32; off >= 1; off >>= 1) s2 += __shfl_xor(s2, off);
    out[(size_t)n * DO + lane] = total / fmaxf(sqrtf(s2), 1e-12f);
}

// ---------------------------------------------------------------------------
// Fallback path (small ws): R1 atomic-scatter pipeline.
// ---------------------------------------------------------------------------
__global__ __launch_bounds__(256) void scatter_kernel(
    const __hip_bfloat16* __restrict__ xwb, const float* __restrict__ vals,
    const int* __restrict__ rows, const int* __restrict__ cols,
    float* __restrict__ agg)
{
    const int nPairs = NE / 2;
    int gwave  = (blockIdx.x * 256 + threadIdx.x) >> 6;
    int half   = (threadIdx.x >> 5) & 1;
    int l32    = threadIdx.x & 31;
    int stride = gridDim.x * 4;
    const uint16_t* xw16 = reinterpret_cast<const uint16_t*>(xwb);
    for (int p = gwave; p < nPairs; p += stride) {
        int e = 2 * p + half;
        int row = rows[e]; int col = cols[e]; float v = vals[e];
        uint32_t packed = *reinterpret_cast<const uint32_t*>(
            xw16 + ((size_t)col << 6) + 2 * l32);
        float f0 = __uint_as_float(packed << 16);
        float f1 = __uint_as_float(packed & 0xFFFF0000u);
        float* dst = agg + ((size_t)row << 6) + 2 * l32;
        atomicAdd(dst,     v * f0);
        atomicAdd(dst + 1, v * f1);
    }
}

__global__ __launch_bounds__(256) void accum_kernel(
    float* __restrict__ agg, const float* __restrict__ b,
    float* __restrict__ out, int first)
{
    int i = blockIdx.x * 256 + threadIdx.x;
    if (i >= NN * DO) return;
    float v = agg[i] + b[i & (DO - 1)];
    agg[i] = 0.f;
    v = fmaxf(v, 0.f);
    out[i] = first ? v : (out[i] + v);
}

__global__ __launch_bounds__(256) void norm_kernel(float* __restrict__ out)
{
    int n = (blockIdx.x * 256 + threadIdx.x) >> 6;
    int lane = threadIdx.x & 63;
    if (n >= NN) return;
    size_t idx = (size_t)n * DO + lane;
    float t = out[idx];
    float s = t * t;
    #pragma unroll
    for (int off = 32; off >= 1; off >>= 1) s += __shfl_xor(s, off);
    out[idx] = t / fmaxf(sqrtf(s), 1e-12f);
}

extern "C" void kernel_launch(void* const* d_in, const int* in_sizes, int n_in,
                              void* d_out, int out_size, void* d_ws, size_t ws_size,
                              hipStream_t stream)
{
    const float* x    = (const float*)d_in[0];
    const float* W    = (const float*)d_in[1];
    const float* b    = (const float*)d_in[2];
    const float* vals = (const float*)d_in[3];
    const int*   rows = (const int*)d_in[4];
    const int*   cols = (const int*)d_in[5];
    float* out = (float*)d_out;
    char* ws = (char*)d_ws;

    // ws: xwb 25.6MB | csr 25.6MB | rowptr 3.2MB | gtot | gstart | gcur
    const size_t O_XW = 0;
    const size_t O_CS = O_XW + (size_t)NR * NN * DO * 2;
    const size_t O_RP = O_CS + (size_t)NR * NE * 8;
    const size_t O_GT = O_RP + ((size_t)NR * NN + 4) * 4;
    const size_t O_GS = O_GT + (size_t)NBUCK * 4;
    const size_t O_GC = O_GS + (size_t)(NBUCK + 1) * 4;
    const size_t NEED = O_GC + (size_t)NBUCK * 4;

    if (ws_size >= NEED) {
        __hip_bfloat16* xwb = (__hip_bfloat16*)(ws + O_XW);
        int2* csr   = (int2*)(ws + O_CS);
        int* rowptr = (int*)(ws + O_RP);
        int* gtot   = (int*)(ws + O_GT);
        int* gstart = (int*)(ws + O_GS);
        int* gcur   = (int*)(ws + O_GC);

        hipMemsetAsync(gtot, 0, (size_t)NBUCK * 4, stream);
        gemm_kernel<<<dim3((NN + 31) / 32, NR), dim3(256), 0, stream>>>(x, W, xwb);
        bhist_kernel<<<dim3(32, NR), dim3(256), 0, stream>>>(rows, gtot);
        bases_kernel<<<dim3(1), dim3(512), 0, stream>>>(gtot, gstart, gcur);
        place_kernel<<<dim3(PWG, NR), dim3(512), 0, stream>>>(rows, cols, vals, gcur, csr);
        rowsort_kernel<<<dim3(NB, NR), dim3(256), 0, stream>>>(csr, gstart, rowptr);
        spmm_fused_kernel<<<dim3((NN * 64 + 255) / 256), dim3(256), 0, stream>>>(
            (const uint16_t*)xwb, csr, rowptr, b, out);
    } else {
        // sequential atomic-scatter fallback (19.2MB)
        __hip_bfloat16* xwb = (__hip_bfloat16*)ws;
        float* agg = (float*)(ws + (size_t)NN * DO * 2);
        hipMemsetAsync(agg, 0, (size_t)NN * DO * 4, stream);
        for (int r = 0; r < NR; ++r) {
            gemm_kernel<<<dim3((NN + 31) / 32, 1), dim3(256), 0, stream>>>(
                x, W + (size_t)r * DI * DO, xwb);
            scatter_kernel<<<dim3(2048), dim3(256), 0, stream>>>(
                xwb, vals + (size_t)r * NE, rows + (size_t)r * NE,
                cols + (size_t)r * NE, agg);
            accum_kernel<<<dim3((NN * DO + 255) / 256), dim3(256), 0, stream>>>(
                agg, b + (size_t)r * DO, out, r == 0);
        }
        norm_kernel<<<dim3((NN * DO + 255) / 256), dim3(256), 0, stream>>>(out);
    }
}

// Round 5
// 315.447 us; speedup vs baseline: 4.7738x; 1.1869x over previous
//
#include <hip/hip_runtime.h>
#include <hip/hip_bf16.h>
#include <stdint.h>

#define NN 50000   // nodes
#define DI 128     // input features
#define DO 64      // output features
#define NE 800000  // edges per relation
#define NR 4       // relations
#define NB 782     // ceil(NN/64) 64-row blocks
#define NBUCK (NR*NB)   // 3128 buckets total
#define PCHUNK 7168     // edges per place workgroup
#define PWG ((NE + PCHUNK - 1) / PCHUNK)   // 112 per relation
#define RSCAP 4096      // rowsort bucket capacity (mean 1023)

// ---------------------------------------------------------------------------
// Block-wide exclusive scan of a[0..N) in LDS. BLK threads, PER elems/thread.
// ---------------------------------------------------------------------------
template<int N, int PER, int BLK>
__device__ inline void block_exscan(int* a)
{
    __shared__ int wsum[BLK / 64];
    int tid = threadIdx.x;
    int base = tid * PER;
    int v[PER]; int s = 0;
    #pragma unroll
    for (int j = 0; j < PER; ++j) {
        int idx = base + j;
        int x = (idx < N) ? a[idx] : 0;
        v[j] = s; s += x;
    }
    int lane = tid & 63, wv = tid >> 6;
    int inc = s;
    #pragma unroll
    for (int off = 1; off < 64; off <<= 1) {
        int u = __shfl_up(inc, off);
        if (lane >= off) inc += u;
    }
    if (lane == 63) wsum[wv] = inc;
    __syncthreads();
    int woff = 0;
    for (int w = 0; w < wv; ++w) woff += wsum[w];
    int tb = woff + inc - s;
    #pragma unroll
    for (int j = 0; j < PER; ++j) {
        int idx = base + j;
        if (idx < N) a[idx] = tb + v[j];
    }
}

// ---------------------------------------------------------------------------
// GEMM: xw[r] = x @ W_r -> bf16 [NN, DO]. blockIdx.y = relation.
// ---------------------------------------------------------------------------
__global__ __launch_bounds__(256) void gemm_kernel(
    const float* __restrict__ x, const float* __restrict__ W,
    __hip_bfloat16* __restrict__ xwb)
{
    int r = blockIdx.y;
    const float* Wr = W + (size_t)r * DI * DO;
    __hip_bfloat16* xwr = xwb + (size_t)r * NN * DO;

    __shared__ float Wl[DI * DO];
    for (int i = threadIdx.x; i < DI * DO; i += 256) Wl[i] = Wr[i];
    __syncthreads();

    int wv   = __builtin_amdgcn_readfirstlane((int)(threadIdx.x >> 6));
    int lane = threadIdx.x & 63;
    int n0   = blockIdx.x * 32 + wv * 8;
    if (n0 >= NN) return;
    int nrows = NN - n0; if (nrows > 8) nrows = 8;

    if (nrows == 8) {
        const float* xr = x + (size_t)n0 * DI;
        float acc[8] = {0.f,0.f,0.f,0.f,0.f,0.f,0.f,0.f};
        #pragma unroll 8
        for (int k = 0; k < DI; ++k) {
            float w = Wl[k * DO + lane];
            #pragma unroll
            for (int rr = 0; rr < 8; ++rr)
                acc[rr] = fmaf(xr[(size_t)rr * DI + k], w, acc[rr]);
        }
        #pragma unroll
        for (int rr = 0; rr < 8; ++rr)
            xwr[(size_t)(n0 + rr) * DO + lane] = __float2bfloat16(acc[rr]);
    } else {
        for (int rr = 0; rr < nrows; ++rr) {
            const float* xr = x + (size_t)(n0 + rr) * DI;
            float acc = 0.f;
            for (int k = 0; k < DI; ++k)
                acc = fmaf(xr[k], Wl[k * DO + lane], acc);
            xwr[(size_t)(n0 + rr) * DO + lane] = __float2bfloat16(acc);
        }
    }
}

// ---------------------------------------------------------------------------
// Bucket histogram (int4-vectorized): gtot[r*NB + row>>6] += 1.
// ---------------------------------------------------------------------------
__global__ __launch_bounds__(256) void bhist_kernel(
    const int* __restrict__ rows, int* __restrict__ gtot)
{
    __shared__ int h[NB];
    int r = blockIdx.y;
    int tid = threadIdx.x;
    for (int i = tid; i < NB; i += 256) h[i] = 0;
    __syncthreads();
    const int4* rr4 = (const int4*)(rows + (size_t)r * NE);
    for (int k = blockIdx.x * 256 + tid; k < NE / 4; k += gridDim.x * 256) {
        int4 v = rr4[k];
        atomicAdd(&h[v.x >> 6], 1);
        atomicAdd(&h[v.y >> 6], 1);
        atomicAdd(&h[v.z >> 6], 1);
        atomicAdd(&h[v.w >> 6], 1);
    }
    __syncthreads();
    int* gt = gtot + r * NB;
    for (int i = tid; i < NB; i += 256)
        if (h[i]) atomicAdd(&gt[i], h[i]);
}

// ---------------------------------------------------------------------------
// Scan bucket totals -> gstart[0..NBUCK] + gcur copy.
// ---------------------------------------------------------------------------
__global__ __launch_bounds__(512) void bases_kernel(
    const int* __restrict__ gtot, int* __restrict__ gstart,
    int* __restrict__ gcur)
{
    __shared__ int a[NBUCK + 1];
    int tid = threadIdx.x;
    for (int i = tid; i < NBUCK + 1; i += 512) a[i] = (i < NBUCK) ? gtot[i] : 0;
    __syncthreads();
    block_exscan<NBUCK + 1, 7, 512>(a);
    __syncthreads();
    for (int i = tid; i < NBUCK + 1; i += 512) {
        gstart[i] = a[i];
        if (i < NBUCK) gcur[i] = a[i];
    }
}

// ---------------------------------------------------------------------------
// Placement: counting-sort a PCHUNK chunk by 64-row bucket in LDS, reserve
// global ranges, flush coalesced. Record: col:16 | rowlow:6 | bucket:10.
// Flush uses the staged bucket bits -> 1 LDS read, no binary search.
// ---------------------------------------------------------------------------
__global__ __launch_bounds__(512) void place_kernel(
    const int* __restrict__ rows, const int* __restrict__ cols,
    const float* __restrict__ vals, int* __restrict__ gcur,
    int2* __restrict__ csr)
{
    __shared__ int lofs[NB + 1];
    __shared__ int gbase[NB];
    __shared__ int2 stag[PCHUNK];
    int r = blockIdx.y;
    int tid = threadIdx.x;
    int e0 = blockIdx.x * PCHUNK;
    int cnt = NE - e0; if (cnt > PCHUNK) cnt = PCHUNK;
    const int*   rr = rows + (size_t)r * NE + e0;
    const int*   cc = cols + (size_t)r * NE + e0;
    const float* vv = vals + (size_t)r * NE + e0;

    for (int i = tid; i <= NB; i += 512) lofs[i] = 0;
    __syncthreads();
    for (int k = tid; k < cnt; k += 512) atomicAdd(&lofs[rr[k] >> 6], 1);
    __syncthreads();
    block_exscan<NB + 1, 2, 512>(lofs);
    __syncthreads();
    for (int b = tid; b < NB; b += 512) {
        int c = lofs[b + 1] - lofs[b];
        if (c > 0) gbase[b] = atomicAdd(&gcur[r * NB + b], c);
    }
    __syncthreads();
    // stage bucket-sorted; after this lofs[b] == end of bucket b's run
    for (int k = tid; k < cnt; k += 512) {
        int row = rr[k];
        int b = row >> 6;
        int slot = atomicAdd(&lofs[b], 1);
        stag[slot] = make_int2((cc[k] & 0xFFFF) | ((row & 63) << 16) | (b << 22),
                               __float_as_int(vv[k]));
    }
    __syncthreads();
    // coalesced flush; bucket read back from staged record
    for (int i = tid; i < cnt; i += 512) {
        int2 t = stag[i];
        unsigned b2 = ((unsigned)t.x) >> 22;
        int start = b2 ? lofs[b2 - 1] : 0;   // lofs[b2-1] == start of bucket b2
        csr[gbase[b2] + (i - start)] = t;
    }
}

// ---------------------------------------------------------------------------
// Within-bucket counting sort by row (in place) + emit per-row rowptr.
// ---------------------------------------------------------------------------
__global__ __launch_bounds__(256) void rowsort_kernel(
    int2* __restrict__ csr, const int* __restrict__ gstart,
    int* __restrict__ rowptr)
{
    __shared__ int2 stag[RSCAP];
    __shared__ int cnt[64];
    __shared__ int ofs[64];
    int blk = blockIdx.x;
    int r   = blockIdx.y;
    int b   = r * NB + blk;
    int s = gstart[b], e = gstart[b + 1];
    int cntE = e - s; if (cntE > RSCAP) cntE = RSCAP;
    int tid = threadIdx.x;
    if (tid < 64) cnt[tid] = 0;
    __syncthreads();

    int2 ed[RSCAP / 256];
    #pragma unroll
    for (int j = 0; j < RSCAP / 256; ++j) {
        int i = tid + j * 256;
        if (i < cntE) {
            ed[j] = csr[s + i];
            atomicAdd(&cnt[(ed[j].x >> 16) & 63], 1);
        }
    }
    __syncthreads();
    if (tid < 64) {
        int c = cnt[tid];
        int inc = c;
        #pragma unroll
        for (int off = 1; off < 64; off <<= 1) {
            int u = __shfl_up(inc, off);
            if (tid >= off) inc += u;
        }
        ofs[tid] = inc - c;                 // exclusive prefix
        int n = blk * 64 + tid;
        if (n < NN) rowptr[(size_t)r * NN + n] = s + inc - c;
        if (b == NBUCK - 1 && tid == 0)
            rowptr[(size_t)NR * NN] = gstart[NBUCK];
    }
    __syncthreads();
    #pragma unroll
    for (int j = 0; j < RSCAP / 256; ++j) {
        int i = tid + j * 256;
        if (i < cntE) {
            int rl = (ed[j].x >> 16) & 63;
            int slot = atomicAdd(&ofs[rl], 1);
            stag[slot] = ed[j];
        }
    }
    __syncthreads();
    for (int i = tid; i < cntE; i += 256) csr[s + i] = stag[i];
}

// ---------------------------------------------------------------------------
// Fused SpMM + bias + relu + sum + L2 normalize.
// One wave per row. Half-wave per edge: lanes 0-31 edge si[r], lanes 32-63
// edge si[r]+1; each lane covers feature pair (2*l2, 2*l2+1) via bf16x2.
// 8 gathers in flight per iteration (4 relations x 2 edges).
// ---------------------------------------------------------------------------
__global__ __launch_bounds__(256) void spmm_fused_kernel(
    const uint32_t* __restrict__ xw32, const int2* __restrict__ csr,
    const int* __restrict__ rowptr, const float* __restrict__ bias,
    float* __restrict__ out)
{
    int n = __builtin_amdgcn_readfirstlane(
        (int)((blockIdx.x * 256 + threadIdx.x) >> 6));
    int lane = threadIdx.x & 63;
    int half = lane >> 5, l2 = lane & 31;
    if (n >= NN) return;

    int si[NR], ei[NR];
    #pragma unroll
    for (int r = 0; r < NR; ++r) {
        si[r] = rowptr[(size_t)r * NN + n];
        ei[r] = rowptr[(size_t)r * NN + n + 1];
    }
    float a0[NR] = {0.f, 0.f, 0.f, 0.f};
    float a1[NR] = {0.f, 0.f, 0.f, 0.f};
    bool any = true;
    while (any) {
        any = false;
        #pragma unroll
        for (int r = 0; r < NR; ++r) {
            if (si[r] < ei[r]) {                       // wave-uniform branch
                int idx = si[r] + half;
                bool valid = idx < ei[r];
                int cidx = valid ? idx : si[r];        // safe in-range clamp
                int2 cv = csr[cidx];
                float v = valid ? __int_as_float(cv.y) : 0.f;
                int col = cv.x & 0xFFFF;
                uint32_t u = xw32[(((size_t)r * NN + col) << 5) + l2];
                a0[r] = fmaf(v, __uint_as_float(u << 16), a0[r]);
                a1[r] = fmaf(v, __uint_as_float(u & 0xFFFF0000u), a1[r]);
                si[r] += 2;
                any = true;
            }
        }
    }
    float t0 = 0.f, t1 = 0.f;
    #pragma unroll
    for (int r = 0; r < NR; ++r) {
        a0[r] += __shfl_xor(a0[r], 32);
        a1[r] += __shfl_xor(a1[r], 32);
        float2 br = *(const float2*)&bias[r * DO + 2 * l2];
        t0 += fmaxf(a0[r] + br.x, 0.f);
        t1 += fmaxf(a1[r] + br.y, 0.f);
    }
    float s2 = t0 * t0 + t1 * t1;
    #pragma unroll
    for (int off = 16; off >= 1; off >>= 1) s2 += __shfl_xor(s2, off);
    float inv = 1.0f / fmaxf(sqrtf(s2), 1e-12f);
    if (half == 0) {
        float2 o = make_float2(t0 * inv, t1 * inv);
        *(float2*)&out[(size_t)n * DO + 2 * l2] = o;
    }
}

// ---------------------------------------------------------------------------
// Fallback path (small ws): R1 atomic-scatter pipeline.
// ---------------------------------------------------------------------------
__global__ __launch_bounds__(256) void scatter_kernel(
    const __hip_bfloat16* __restrict__ xwb, const float* __restrict__ vals,
    const int* __restrict__ rows, const int* __restrict__ cols,
    float* __restrict__ agg)
{
    const int nPairs = NE / 2;
    int gwave  = (blockIdx.x * 256 + threadIdx.x) >> 6;
    int half   = (threadIdx.x >> 5) & 1;
    int l32    = threadIdx.x & 31;
    int stride = gridDim.x * 4;
    const uint16_t* xw16 = reinterpret_cast<const uint16_t*>(xwb);
    for (int p = gwave; p < nPairs; p += stride) {
        int e = 2 * p + half;
        int row = rows[e]; int col = cols[e]; float v = vals[e];
        uint32_t packed = *reinterpret_cast<const uint32_t*>(
            xw16 + ((size_t)col << 6) + 2 * l32);
        float f0 = __uint_as_float(packed << 16);
        float f1 = __uint_as_float(packed & 0xFFFF0000u);
        float* dst = agg + ((size_t)row << 6) + 2 * l32;
        atomicAdd(dst,     v * f0);
        atomicAdd(dst + 1, v * f1);
    }
}

__global__ __launch_bounds__(256) void accum_kernel(
    float* __restrict__ agg, const float* __restrict__ b,
    float* __restrict__ out, int first)
{
    int i = blockIdx.x * 256 + threadIdx.x;
    if (i >= NN * DO) return;
    float v = agg[i] + b[i & (DO - 1)];
    agg[i] = 0.f;
    v = fmaxf(v, 0.f);
    out[i] = first ? v : (out[i] + v);
}

__global__ __launch_bounds__(256) void norm_kernel(float* __restrict__ out)
{
    int n = (blockIdx.x * 256 + threadIdx.x) >> 6;
    int lane = threadIdx.x & 63;
    if (n >= NN) return;
    size_t idx = (size_t)n * DO + lane;
    float t = out[idx];
    float s = t * t;
    #pragma unroll
    for (int off = 32; off >= 1; off >>= 1) s += __shfl_xor(s, off);
    out[idx] = t / fmaxf(sqrtf(s), 1e-12f);
}

extern "C" void kernel_launch(void* const* d_in, const int* in_sizes, int n_in,
                              void* d_out, int out_size, void* d_ws, size_t ws_size,
                              hipStream_t stream)
{
    const float* x    = (const float*)d_in[0];
    const float* W    = (const float*)d_in[1];
    const float* b    = (const float*)d_in[2];
    const float* vals = (const float*)d_in[3];
    const int*   rows = (const int*)d_in[4];
    const int*   cols = (const int*)d_in[5];
    float* out = (float*)d_out;
    char* ws = (char*)d_ws;

    // ws: xwb 25.6MB | csr 25.6MB | rowptr 3.2MB | gtot | gstart | gcur
    const size_t O_XW = 0;
    const size_t O_CS = O_XW + (size_t)NR * NN * DO * 2;
    const size_t O_RP = O_CS + (size_t)NR * NE * 8;
    const size_t O_GT = O_RP + ((size_t)NR * NN + 4) * 4;
    const size_t O_GS = O_GT + (size_t)NBUCK * 4;
    const size_t O_GC = O_GS + (size_t)(NBUCK + 1) * 4;
    const size_t NEED = O_GC + (size_t)NBUCK * 4;

    if (ws_size >= NEED) {
        __hip_bfloat16* xwb = (__hip_bfloat16*)(ws + O_XW);
        int2* csr   = (int2*)(ws + O_CS);
        int* rowptr = (int*)(ws + O_RP);
        int* gtot   = (int*)(ws + O_GT);
        int* gstart = (int*)(ws + O_GS);
        int* gcur   = (int*)(ws + O_GC);

        hipMemsetAsync(gtot, 0, (size_t)NBUCK * 4, stream);
        gemm_kernel<<<dim3((NN + 31) / 32, NR), dim3(256), 0, stream>>>(x, W, xwb);
        bhist_kernel<<<dim3(32, NR), dim3(256), 0, stream>>>(rows, gtot);
        bases_kernel<<<dim3(1), dim3(512), 0, stream>>>(gtot, gstart, gcur);
        place_kernel<<<dim3(PWG, NR), dim3(512), 0, stream>>>(rows, cols, vals, gcur, csr);
        rowsort_kernel<<<dim3(NB, NR), dim3(256), 0, stream>>>(csr, gstart, rowptr);
        spmm_fused_kernel<<<dim3((NN * 64 + 255) / 256), dim3(256), 0, stream>>>(
            (const uint32_t*)xwb, csr, rowptr, b, out);
    } else {
        // sequential atomic-scatter fallback (19.2MB)
        __hip_bfloat16* xwb = (__hip_bfloat16*)ws;
        float* agg = (float*)(ws + (size_t)NN * DO * 2);
        hipMemsetAsync(agg, 0, (size_t)NN * DO * 4, stream);
        for (int r = 0; r < NR; ++r) {
            gemm_kernel<<<dim3((NN + 31) / 32, 1), dim3(256), 0, stream>>>(
                x, W + (size_t)r * DI * DO, xwb);
            scatter_kernel<<<dim3(2048), dim3(256), 0, stream>>>(
                xwb, vals + (size_t)r * NE, rows + (size_t)r * NE,
                cols + (size_t)r * NE, agg);
            accum_kernel<<<dim3((NN * DO + 255) / 256), dim3(256), 0, stream>>>(
                agg, b + (size_t)r * DO, out, r == 0);
        }
        norm_kernel<<<dim3((NN * DO + 255) / 256), dim3(256), 0, stream>>>(out);
    }
}

// Round 6
// 232.572 us; speedup vs baseline: 6.4749x; 1.3563x over previous
//
#include <hip/hip_runtime.h>
#include <hip/hip_bf16.h>
#include <stdint.h>

#define NN 50000   // nodes
#define DI 128     // input features
#define DO 64      // output features
#define NE 800000  // edges per relation
#define NR 4       // relations
#define NB 782     // ceil(NN/64) 64-row blocks
#define NBUCK (NR*NB)   // 3128 buckets total
#define PCHUNK 7168     // edges per place workgroup
#define PWG ((NE + PCHUNK - 1) / PCHUNK)   // 112 per relation
#define RSCAP 4096      // rowsort bucket capacity (mean 1023)

// ---------------------------------------------------------------------------
// Block-wide exclusive scan of a[0..N) in LDS. BLK threads, PER elems/thread.
// ---------------------------------------------------------------------------
template<int N, int PER, int BLK>
__device__ inline void block_exscan(int* a)
{
    __shared__ int wsum[BLK / 64];
    int tid = threadIdx.x;
    int base = tid * PER;
    int v[PER]; int s = 0;
    #pragma unroll
    for (int j = 0; j < PER; ++j) {
        int idx = base + j;
        int x = (idx < N) ? a[idx] : 0;
        v[j] = s; s += x;
    }
    int lane = tid & 63, wv = tid >> 6;
    int inc = s;
    #pragma unroll
    for (int off = 1; off < 64; off <<= 1) {
        int u = __shfl_up(inc, off);
        if (lane >= off) inc += u;
    }
    if (lane == 63) wsum[wv] = inc;
    __syncthreads();
    int woff = 0;
    for (int w = 0; w < wv; ++w) woff += wsum[w];
    int tb = woff + inc - s;
    #pragma unroll
    for (int j = 0; j < PER; ++j) {
        int idx = base + j;
        if (idx < N) a[idx] = tb + v[j];
    }
}

// ---------------------------------------------------------------------------
// GEMM: xw[r] = x @ W_r -> bf16 [NN, DO]. blockIdx.y = relation.
// ---------------------------------------------------------------------------
__global__ __launch_bounds__(256) void gemm_kernel(
    const float* __restrict__ x, const float* __restrict__ W,
    __hip_bfloat16* __restrict__ xwb)
{
    int r = blockIdx.y;
    const float* Wr = W + (size_t)r * DI * DO;
    __hip_bfloat16* xwr = xwb + (size_t)r * NN * DO;

    __shared__ float Wl[DI * DO];
    for (int i = threadIdx.x; i < DI * DO; i += 256) Wl[i] = Wr[i];
    __syncthreads();

    int wv   = __builtin_amdgcn_readfirstlane((int)(threadIdx.x >> 6));
    int lane = threadIdx.x & 63;
    int n0   = blockIdx.x * 32 + wv * 8;
    if (n0 >= NN) return;
    int nrows = NN - n0; if (nrows > 8) nrows = 8;

    if (nrows == 8) {
        const float* xr = x + (size_t)n0 * DI;
        float acc[8] = {0.f,0.f,0.f,0.f,0.f,0.f,0.f,0.f};
        #pragma unroll 8
        for (int k = 0; k < DI; ++k) {
            float w = Wl[k * DO + lane];
            #pragma unroll
            for (int rr = 0; rr < 8; ++rr)
                acc[rr] = fmaf(xr[(size_t)rr * DI + k], w, acc[rr]);
        }
        #pragma unroll
        for (int rr = 0; rr < 8; ++rr)
            xwr[(size_t)(n0 + rr) * DO + lane] = __float2bfloat16(acc[rr]);
    } else {
        for (int rr = 0; rr < nrows; ++rr) {
            const float* xr = x + (size_t)(n0 + rr) * DI;
            float acc = 0.f;
            for (int k = 0; k < DI; ++k)
                acc = fmaf(xr[k], Wl[k * DO + lane], acc);
            xwr[(size_t)(n0 + rr) * DO + lane] = __float2bfloat16(acc);
        }
    }
}

// ---------------------------------------------------------------------------
// Bucket histogram (int4-vectorized): gtot[r*NB + row>>6] += 1.
// ---------------------------------------------------------------------------
__global__ __launch_bounds__(256) void bhist_kernel(
    const int* __restrict__ rows, int* __restrict__ gtot)
{
    __shared__ int h[NB];
    int r = blockIdx.y;
    int tid = threadIdx.x;
    for (int i = tid; i < NB; i += 256) h[i] = 0;
    __syncthreads();
    const int4* rr4 = (const int4*)(rows + (size_t)r * NE);
    for (int k = blockIdx.x * 256 + tid; k < NE / 4; k += gridDim.x * 256) {
        int4 v = rr4[k];
        atomicAdd(&h[v.x >> 6], 1);
        atomicAdd(&h[v.y >> 6], 1);
        atomicAdd(&h[v.z >> 6], 1);
        atomicAdd(&h[v.w >> 6], 1);
    }
    __syncthreads();
    int* gt = gtot + r * NB;
    for (int i = tid; i < NB; i += 256)
        if (h[i]) atomicAdd(&gt[i], h[i]);
}

// ---------------------------------------------------------------------------
// Scan bucket totals -> gstart[0..NBUCK] + gcur copy.
// ---------------------------------------------------------------------------
__global__ __launch_bounds__(512) void bases_kernel(
    const int* __restrict__ gtot, int* __restrict__ gstart,
    int* __restrict__ gcur)
{
    __shared__ int a[NBUCK + 1];
    int tid = threadIdx.x;
    for (int i = tid; i < NBUCK + 1; i += 512) a[i] = (i < NBUCK) ? gtot[i] : 0;
    __syncthreads();
    block_exscan<NBUCK + 1, 7, 512>(a);
    __syncthreads();
    for (int i = tid; i < NBUCK + 1; i += 512) {
        gstart[i] = a[i];
        if (i < NBUCK) gcur[i] = a[i];
    }
}

// ---------------------------------------------------------------------------
// Placement: counting-sort a PCHUNK chunk by 64-row bucket in LDS, reserve
// global ranges, flush coalesced. Record: col:16 | rowlow:6 | bucket:10.
// ---------------------------------------------------------------------------
__global__ __launch_bounds__(512) void place_kernel(
    const int* __restrict__ rows, const int* __restrict__ cols,
    const float* __restrict__ vals, int* __restrict__ gcur,
    int2* __restrict__ csr)
{
    __shared__ int lofs[NB + 1];
    __shared__ int gbase[NB];
    __shared__ int2 stag[PCHUNK];
    int r = blockIdx.y;
    int tid = threadIdx.x;
    int e0 = blockIdx.x * PCHUNK;
    int cnt = NE - e0; if (cnt > PCHUNK) cnt = PCHUNK;
    const int*   rr = rows + (size_t)r * NE + e0;
    const int*   cc = cols + (size_t)r * NE + e0;
    const float* vv = vals + (size_t)r * NE + e0;

    for (int i = tid; i <= NB; i += 512) lofs[i] = 0;
    __syncthreads();
    for (int k = tid; k < cnt; k += 512) atomicAdd(&lofs[rr[k] >> 6], 1);
    __syncthreads();
    block_exscan<NB + 1, 2, 512>(lofs);
    __syncthreads();
    for (int b = tid; b < NB; b += 512) {
        int c = lofs[b + 1] - lofs[b];
        if (c > 0) gbase[b] = atomicAdd(&gcur[r * NB + b], c);
    }
    __syncthreads();
    for (int k = tid; k < cnt; k += 512) {
        int row = rr[k];
        int b = row >> 6;
        int slot = atomicAdd(&lofs[b], 1);
        stag[slot] = make_int2((cc[k] & 0xFFFF) | ((row & 63) << 16) | (b << 22),
                               __float_as_int(vv[k]));
    }
    __syncthreads();
    for (int i = tid; i < cnt; i += 512) {
        int2 t = stag[i];
        unsigned b2 = ((unsigned)t.x) >> 22;
        int start = b2 ? lofs[b2 - 1] : 0;
        csr[gbase[b2] + (i - start)] = t;
    }
}

// ---------------------------------------------------------------------------
// Within-bucket counting sort by row (in place) + emit per-row rowptr.
// ---------------------------------------------------------------------------
__global__ __launch_bounds__(256) void rowsort_kernel(
    int2* __restrict__ csr, const int* __restrict__ gstart,
    int* __restrict__ rowptr)
{
    __shared__ int2 stag[RSCAP];
    __shared__ int cnt[64];
    __shared__ int ofs[64];
    int blk = blockIdx.x;
    int r   = blockIdx.y;
    int b   = r * NB + blk;
    int s = gstart[b], e = gstart[b + 1];
    int cntE = e - s; if (cntE > RSCAP) cntE = RSCAP;
    int tid = threadIdx.x;
    if (tid < 64) cnt[tid] = 0;
    __syncthreads();

    int2 ed[RSCAP / 256];
    #pragma unroll
    for (int j = 0; j < RSCAP / 256; ++j) {
        int i = tid + j * 256;
        if (i < cntE) {
            ed[j] = csr[s + i];
            atomicAdd(&cnt[(ed[j].x >> 16) & 63], 1);
        }
    }
    __syncthreads();
    if (tid < 64) {
        int c = cnt[tid];
        int inc = c;
        #pragma unroll
        for (int off = 1; off < 64; off <<= 1) {
            int u = __shfl_up(inc, off);
            if (tid >= off) inc += u;
        }
        ofs[tid] = inc - c;
        int n = blk * 64 + tid;
        if (n < NN) rowptr[(size_t)r * NN + n] = s + inc - c;
        if (b == NBUCK - 1 && tid == 0)
            rowptr[(size_t)NR * NN] = gstart[NBUCK];
    }
    __syncthreads();
    #pragma unroll
    for (int j = 0; j < RSCAP / 256; ++j) {
        int i = tid + j * 256;
        if (i < cntE) {
            int rl = (ed[j].x >> 16) & 63;
            int slot = atomicAdd(&ofs[rl], 1);
            stag[slot] = ed[j];
        }
    }
    __syncthreads();
    for (int i = tid; i < cntE; i += 256) csr[s + i] = stag[i];
}

// ---------------------------------------------------------------------------
// Fused SpMM v3: metadata-in-register + 2-stage software pipeline.
// One wave per row. Edge records (<=64/relation) loaded coalesced into
// registers (lane i = edge i); col/val via __shfl (no VMEM on critical
// path). Stage = 4 relations x 2 half-edges = 8 gathers; issue(k+4) before
// consume(k) -> 16 gathers in flight.
// ---------------------------------------------------------------------------
struct Stage {
    float    v[NR][2];
    uint32_t u[NR][2];
};

__device__ __forceinline__ void stage_issue(
    int k, const int* deg, const int* colv, const float* valv,
    const uint32_t* __restrict__ xw32, int half, int l2, Stage& st)
{
    #pragma unroll
    for (int r = 0; r < NR; ++r) {
        if (k < deg[r]) {                      // wave-uniform
            #pragma unroll
            for (int sub = 0; sub < 2; ++sub) {
                int e = k + 2 * sub + half;
                bool valid = e < deg[r];
                int ec = valid ? e : 0;
                int col = __shfl(colv[r], ec);
                float v = __shfl(valv[r], ec);
                st.v[r][sub] = valid ? v : 0.f;
                st.u[r][sub] = xw32[(((size_t)r * NN + col) << 5) + l2];
            }
        } else {
            #pragma unroll
            for (int sub = 0; sub < 2; ++sub) {
                st.v[r][sub] = 0.f;
                st.u[r][sub] = 0u;             // avoid 0*garbage NaN
            }
        }
    }
}

__device__ __forceinline__ void stage_consume(
    const Stage& st, float* a0, float* a1)
{
    #pragma unroll
    for (int r = 0; r < NR; ++r) {
        #pragma unroll
        for (int sub = 0; sub < 2; ++sub) {
            a0[r] = fmaf(st.v[r][sub],
                         __uint_as_float(st.u[r][sub] << 16), a0[r]);
            a1[r] = fmaf(st.v[r][sub],
                         __uint_as_float(st.u[r][sub] & 0xFFFF0000u), a1[r]);
        }
    }
}

__global__ __launch_bounds__(256) void spmm_fused_kernel(
    const uint32_t* __restrict__ xw32, const int2* __restrict__ csr,
    const int* __restrict__ rowptr, const float* __restrict__ bias,
    float* __restrict__ out)
{
    int n = __builtin_amdgcn_readfirstlane(
        (int)((blockIdx.x * 256 + threadIdx.x) >> 6));
    int lane = threadIdx.x & 63;
    int half = lane >> 5, l2 = lane & 31;
    if (n >= NN) return;

    int deg[NR]; int colv[NR]; float valv[NR];
    int sbeg[NR], send[NR];
    int maxdeg = 0;
    #pragma unroll
    for (int r = 0; r < NR; ++r) {
        sbeg[r] = rowptr[(size_t)r * NN + n];
        send[r] = rowptr[(size_t)r * NN + n + 1];
        int d = send[r] - sbeg[r];
        if (d > 64) d = 64;
        deg[r] = d;
        int2 cv = (lane < d) ? csr[sbeg[r] + lane] : make_int2(0, 0);
        colv[r] = cv.x & 0xFFFF;
        valv[r] = __int_as_float(cv.y);
        maxdeg = max(maxdeg, d);
    }

    float a0[NR] = {0.f,0.f,0.f,0.f};
    float a1[NR] = {0.f,0.f,0.f,0.f};

    Stage A, B;
    stage_issue(0, deg, colv, valv, xw32, half, l2, A);
    for (int k = 0; k < maxdeg; k += 8) {
        stage_issue(k + 4, deg, colv, valv, xw32, half, l2, B);
        stage_consume(A, a0, a1);
        stage_issue(k + 8, deg, colv, valv, xw32, half, l2, A);
        stage_consume(B, a0, a1);
    }

    // rare tail: deg > 64 (broadcast loop; half 0 accumulates only)
    #pragma unroll
    for (int r = 0; r < NR; ++r) {
        for (int i = sbeg[r] + 64; i < send[r]; ++i) {   // ~never taken
            int2 cv = csr[i];
            float v = (half == 0) ? __int_as_float(cv.y) : 0.f;
            int col = cv.x & 0xFFFF;
            uint32_t u = xw32[(((size_t)r * NN + col) << 5) + l2];
            a0[r] = fmaf(v, __uint_as_float(u << 16), a0[r]);
            a1[r] = fmaf(v, __uint_as_float(u & 0xFFFF0000u), a1[r]);
        }
    }

    float t0 = 0.f, t1 = 0.f;
    #pragma unroll
    for (int r = 0; r < NR; ++r) {
        a0[r] += __shfl_xor(a0[r], 32);
        a1[r] += __shfl_xor(a1[r], 32);
        float2 br = *(const float2*)&bias[r * DO + 2 * l2];
        t0 += fmaxf(a0[r] + br.x, 0.f);
        t1 += fmaxf(a1[r] + br.y, 0.f);
    }
    float s2 = t0 * t0 + t1 * t1;
    #pragma unroll
    for (int off = 16; off >= 1; off >>= 1) s2 += __shfl_xor(s2, off);
    float inv = 1.0f / fmaxf(sqrtf(s2), 1e-12f);
    if (half == 0) {
        float2 o = make_float2(t0 * inv, t1 * inv);
        *(float2*)&out[(size_t)n * DO + 2 * l2] = o;
    }
}

// ---------------------------------------------------------------------------
// Fallback path (small ws): R1 atomic-scatter pipeline.
// ---------------------------------------------------------------------------
__global__ __launch_bounds__(256) void scatter_kernel(
    const __hip_bfloat16* __restrict__ xwb, const float* __restrict__ vals,
    const int* __restrict__ rows, const int* __restrict__ cols,
    float* __restrict__ agg)
{
    const int nPairs = NE / 2;
    int gwave  = (blockIdx.x * 256 + threadIdx.x) >> 6;
    int half   = (threadIdx.x >> 5) & 1;
    int l32    = threadIdx.x & 31;
    int stride = gridDim.x * 4;
    const uint16_t* xw16 = reinterpret_cast<const uint16_t*>(xwb);
    for (int p = gwave; p < nPairs; p += stride) {
        int e = 2 * p + half;
        int row = rows[e]; int col = cols[e]; float v = vals[e];
        uint32_t packed = *reinterpret_cast<const uint32_t*>(
            xw16 + ((size_t)col << 6) + 2 * l32);
        float f0 = __uint_as_float(packed << 16);
        float f1 = __uint_as_float(packed & 0xFFFF0000u);
        float* dst = agg + ((size_t)row << 6) + 2 * l32;
        atomicAdd(dst,     v * f0);
        atomicAdd(dst + 1, v * f1);
    }
}

__global__ __launch_bounds__(256) void accum_kernel(
    float* __restrict__ agg, const float* __restrict__ b,
    float* __restrict__ out, int first)
{
    int i = blockIdx.x * 256 + threadIdx.x;
    if (i >= NN * DO) return;
    float v = agg[i] + b[i & (DO - 1)];
    agg[i] = 0.f;
    v = fmaxf(v, 0.f);
    out[i] = first ? v : (out[i] + v);
}

__global__ __launch_bounds__(256) void norm_kernel(float* __restrict__ out)
{
    int n = (blockIdx.x * 256 + threadIdx.x) >> 6;
    int lane = threadIdx.x & 63;
    if (n >= NN) return;
    size_t idx = (size_t)n * DO + lane;
    float t = out[idx];
    float s = t * t;
    #pragma unroll
    for (int off = 32; off >= 1; off >>= 1) s += __shfl_xor(s, off);
    out[idx] = t / fmaxf(sqrtf(s), 1e-12f);
}

extern "C" void kernel_launch(void* const* d_in, const int* in_sizes, int n_in,
                              void* d_out, int out_size, void* d_ws, size_t ws_size,
                              hipStream_t stream)
{
    const float* x    = (const float*)d_in[0];
    const float* W    = (const float*)d_in[1];
    const float* b    = (const float*)d_in[2];
    const float* vals = (const float*)d_in[3];
    const int*   rows = (const int*)d_in[4];
    const int*   cols = (const int*)d_in[5];
    float* out = (float*)d_out;
    char* ws = (char*)d_ws;

    // ws: xwb 25.6MB | csr 25.6MB | rowptr 3.2MB | gtot | gstart | gcur
    const size_t O_XW = 0;
    const size_t O_CS = O_XW + (size_t)NR * NN * DO * 2;
    const size_t O_RP = O_CS + (size_t)NR * NE * 8;
    const size_t O_GT = O_RP + ((size_t)NR * NN + 4) * 4;
    const size_t O_GS = O_GT + (size_t)NBUCK * 4;
    const size_t O_GC = O_GS + (size_t)(NBUCK + 1) * 4;
    const size_t NEED = O_GC + (size_t)NBUCK * 4;

    if (ws_size >= NEED) {
        __hip_bfloat16* xwb = (__hip_bfloat16*)(ws + O_XW);
        int2* csr   = (int2*)(ws + O_CS);
        int* rowptr = (int*)(ws + O_RP);
        int* gtot   = (int*)(ws + O_GT);
        int* gstart = (int*)(ws + O_GS);
        int* gcur   = (int*)(ws + O_GC);

        hipMemsetAsync(gtot, 0, (size_t)NBUCK * 4, stream);
        gemm_kernel<<<dim3((NN + 31) / 32, NR), dim3(256), 0, stream>>>(x, W, xwb);
        bhist_kernel<<<dim3(32, NR), dim3(256), 0, stream>>>(rows, gtot);
        bases_kernel<<<dim3(1), dim3(512), 0, stream>>>(gtot, gstart, gcur);
        place_kernel<<<dim3(PWG, NR), dim3(512), 0, stream>>>(rows, cols, vals, gcur, csr);
        rowsort_kernel<<<dim3(NB, NR), dim3(256), 0, stream>>>(csr, gstart, rowptr);
        spmm_fused_kernel<<<dim3((NN * 64 + 255) / 256), dim3(256), 0, stream>>>(
            (const uint32_t*)xwb, csr, rowptr, b, out);
    } else {
        // sequential atomic-scatter fallback (19.2MB)
        __hip_bfloat16* xwb = (__hip_bfloat16*)ws;
        float* agg = (float*)(ws + (size_t)NN * DO * 2);
        hipMemsetAsync(agg, 0, (size_t)NN * DO * 4, stream);
        for (int r = 0; r < NR; ++r) {
            gemm_kernel<<<dim3((NN + 31) / 32, 1), dim3(256), 0, stream>>>(
                x, W + (size_t)r * DI * DO, xwb);
            scatter_kernel<<<dim3(2048), dim3(256), 0, stream>>>(
                xwb, vals + (size_t)r * NE, rows + (size_t)r * NE,
                cols + (size_t)r * NE, agg);
            accum_kernel<<<dim3((NN * DO + 255) / 256), dim3(256), 0, stream>>>(
                agg, b + (size_t)r * DO, out, r == 0);
        }
        norm_kernel<<<dim3((NN * DO + 255) / 256), dim3(256), 0, stream>>>(out);
    }
}

// Round 7
// 220.727 us; speedup vs baseline: 6.8224x; 1.0537x over previous
//
#include <hip/hip_runtime.h>
#include <hip/hip_bf16.h>
#include <stdint.h>

#define NN 50000   // nodes
#define DI 128     // input features
#define DO 64      // output features
#define NE 800000  // edges per relation
#define NR 4       // relations
#define NB 782     // ceil(NN/64) 64-row blocks
#define NBUCK (NR*NB)   // 3128 buckets total
#define PCHUNK 7168     // edges per place workgroup
#define PWG ((NE + PCHUNK - 1) / PCHUNK)   // 112 per relation
#define RSCAP 4096      // rowsort bucket capacity (mean 1023)
#define GR 64           // gemm rows per block

// ---------------------------------------------------------------------------
// Block-wide exclusive scan of a[0..N) in LDS. BLK threads, PER elems/thread.
// ---------------------------------------------------------------------------
template<int N, int PER, int BLK>
__device__ inline void block_exscan(int* a)
{
    __shared__ int wsum[BLK / 64];
    int tid = threadIdx.x;
    int base = tid * PER;
    int v[PER]; int s = 0;
    #pragma unroll
    for (int j = 0; j < PER; ++j) {
        int idx = base + j;
        int x = (idx < N) ? a[idx] : 0;
        v[j] = s; s += x;
    }
    int lane = tid & 63, wv = tid >> 6;
    int inc = s;
    #pragma unroll
    for (int off = 1; off < 64; off <<= 1) {
        int u = __shfl_up(inc, off);
        if (lane >= off) inc += u;
    }
    if (lane == 63) wsum[wv] = inc;
    __syncthreads();
    int woff = 0;
    for (int w = 0; w < wv; ++w) woff += wsum[w];
    int tb = woff + inc - s;
    #pragma unroll
    for (int j = 0; j < PER; ++j) {
        int idx = base + j;
        if (idx < N) a[idx] = tb + v[j];
    }
}

__device__ __forceinline__ uint32_t bfb(float f)
{
    __hip_bfloat16 h = __float2bfloat16(f);
    return (uint32_t)*reinterpret_cast<unsigned short*>(&h);
}

// ---------------------------------------------------------------------------
// GEMM v2 (fused path): one block = 64 rows staged once in LDS; wave =
// relation; lane = row. Per k: 1 ds_read (x broadcast-free, per-lane row)
// + 64 FMAs with W from wave-uniform s_load (L2-hot). acc[64] cols/lane.
// x HBM traffic: 25.6MB once (was 4x). Epilogue: row-contiguous bf16 stores.
// ---------------------------------------------------------------------------
__global__ __launch_bounds__(256) void gemm4_kernel(
    const float* __restrict__ x, const float* __restrict__ W,
    __hip_bfloat16* __restrict__ xwb)
{
    __shared__ float xs[GR][DI + 4];   // +4 pad: float4-aligned rows, 8-way banks
    int tid = threadIdx.x;
    int n0 = blockIdx.x * GR;

    const float4* xg = (const float4*)x;
    #pragma unroll
    for (int j = 0; j < 8; ++j) {      // 64 rows * 32 float4 / 256 thr = 8
        int i = tid + j * 256;
        int rr = i >> 5, c4 = i & 31;
        int n = n0 + rr;
        float4 v = (n < NN) ? xg[(size_t)n * 32 + c4]
                            : make_float4(0.f, 0.f, 0.f, 0.f);
        *(float4*)&xs[rr][c4 * 4] = v;
    }
    __syncthreads();

    int r = __builtin_amdgcn_readfirstlane(tid >> 6);   // wave = relation
    int lane = tid & 63;                                // lane = row
    const float* Wr = W + (size_t)r * DI * DO;

    float acc[DO];
    #pragma unroll
    for (int c = 0; c < DO; ++c) acc[c] = 0.f;

    for (int k = 0; k < DI; ++k) {
        float xv = xs[lane][k];
        const float* Wk = Wr + k * DO;   // wave-uniform -> s_load
        #pragma unroll
        for (int c = 0; c < DO; ++c)
            acc[c] = fmaf(xv, Wk[c], acc[c]);
    }

    int n = n0 + lane;
    if (n < NN) {
        uint4* orow = (uint4*)(xwb + ((size_t)r * NN + n) * DO);
        #pragma unroll
        for (int j = 0; j < 8; ++j) {
            uint4 pk;
            pk.x = bfb(acc[8*j+0]) | (bfb(acc[8*j+1]) << 16);
            pk.y = bfb(acc[8*j+2]) | (bfb(acc[8*j+3]) << 16);
            pk.z = bfb(acc[8*j+4]) | (bfb(acc[8*j+5]) << 16);
            pk.w = bfb(acc[8*j+6]) | (bfb(acc[8*j+7]) << 16);
            orow[j] = pk;
        }
    }
}

// ---------------------------------------------------------------------------
// GEMM v1 (fallback path only): per-relation, W in LDS, x via s_load.
// ---------------------------------------------------------------------------
__global__ __launch_bounds__(256) void gemm_kernel(
    const float* __restrict__ x, const float* __restrict__ W,
    __hip_bfloat16* __restrict__ xwb)
{
    __shared__ float Wl[DI * DO];
    for (int i = threadIdx.x; i < DI * DO; i += 256) Wl[i] = W[i];
    __syncthreads();

    int wv   = __builtin_amdgcn_readfirstlane((int)(threadIdx.x >> 6));
    int lane = threadIdx.x & 63;
    int n0   = blockIdx.x * 32 + wv * 8;
    if (n0 >= NN) return;
    int nrows = NN - n0; if (nrows > 8) nrows = 8;

    if (nrows == 8) {
        const float* xr = x + (size_t)n0 * DI;
        float acc[8] = {0.f,0.f,0.f,0.f,0.f,0.f,0.f,0.f};
        #pragma unroll 8
        for (int k = 0; k < DI; ++k) {
            float w = Wl[k * DO + lane];
            #pragma unroll
            for (int rr = 0; rr < 8; ++rr)
                acc[rr] = fmaf(xr[(size_t)rr * DI + k], w, acc[rr]);
        }
        #pragma unroll
        for (int rr = 0; rr < 8; ++rr)
            xwb[(size_t)(n0 + rr) * DO + lane] = __float2bfloat16(acc[rr]);
    } else {
        for (int rr = 0; rr < nrows; ++rr) {
            const float* xr = x + (size_t)(n0 + rr) * DI;
            float acc = 0.f;
            for (int k = 0; k < DI; ++k)
                acc = fmaf(xr[k], Wl[k * DO + lane], acc);
            xwb[(size_t)(n0 + rr) * DO + lane] = __float2bfloat16(acc);
        }
    }
}

// ---------------------------------------------------------------------------
// Bucket histogram (int4-vectorized): gtot[r*NB + row>>6] += 1.
// ---------------------------------------------------------------------------
__global__ __launch_bounds__(256) void bhist_kernel(
    const int* __restrict__ rows, int* __restrict__ gtot)
{
    __shared__ int h[NB];
    int r = blockIdx.y;
    int tid = threadIdx.x;
    for (int i = tid; i < NB; i += 256) h[i] = 0;
    __syncthreads();
    const int4* rr4 = (const int4*)(rows + (size_t)r * NE);
    for (int k = blockIdx.x * 256 + tid; k < NE / 4; k += gridDim.x * 256) {
        int4 v = rr4[k];
        atomicAdd(&h[v.x >> 6], 1);
        atomicAdd(&h[v.y >> 6], 1);
        atomicAdd(&h[v.z >> 6], 1);
        atomicAdd(&h[v.w >> 6], 1);
    }
    __syncthreads();
    int* gt = gtot + r * NB;
    for (int i = tid; i < NB; i += 256)
        if (h[i]) atomicAdd(&gt[i], h[i]);
}

// ---------------------------------------------------------------------------
// Scan bucket totals -> gstart[0..NBUCK] + gcur copy.
// ---------------------------------------------------------------------------
__global__ __launch_bounds__(512) void bases_kernel(
    const int* __restrict__ gtot, int* __restrict__ gstart,
    int* __restrict__ gcur)
{
    __shared__ int a[NBUCK + 1];
    int tid = threadIdx.x;
    for (int i = tid; i < NBUCK + 1; i += 512) a[i] = (i < NBUCK) ? gtot[i] : 0;
    __syncthreads();
    block_exscan<NBUCK + 1, 7, 512>(a);
    __syncthreads();
    for (int i = tid; i < NBUCK + 1; i += 512) {
        gstart[i] = a[i];
        if (i < NBUCK) gcur[i] = a[i];
    }
}

// ---------------------------------------------------------------------------
// Placement: counting-sort a PCHUNK chunk by 64-row bucket in LDS, reserve
// global ranges, flush coalesced. Record: col:16 | rowlow:6 | bucket:10.
// ---------------------------------------------------------------------------
__global__ __launch_bounds__(512) void place_kernel(
    const int* __restrict__ rows, const int* __restrict__ cols,
    const float* __restrict__ vals, int* __restrict__ gcur,
    int2* __restrict__ csr)
{
    __shared__ int lofs[NB + 1];
    __shared__ int gbase[NB];
    __shared__ int2 stag[PCHUNK];
    int r = blockIdx.y;
    int tid = threadIdx.x;
    int e0 = blockIdx.x * PCHUNK;
    int cnt = NE - e0; if (cnt > PCHUNK) cnt = PCHUNK;
    const int*   rr = rows + (size_t)r * NE + e0;
    const int*   cc = cols + (size_t)r * NE + e0;
    const float* vv = vals + (size_t)r * NE + e0;

    for (int i = tid; i <= NB; i += 512) lofs[i] = 0;
    __syncthreads();
    for (int k = tid; k < cnt; k += 512) atomicAdd(&lofs[rr[k] >> 6], 1);
    __syncthreads();
    block_exscan<NB + 1, 2, 512>(lofs);
    __syncthreads();
    for (int b = tid; b < NB; b += 512) {
        int c = lofs[b + 1] - lofs[b];
        if (c > 0) gbase[b] = atomicAdd(&gcur[r * NB + b], c);
    }
    __syncthreads();
    for (int k = tid; k < cnt; k += 512) {
        int row = rr[k];
        int b = row >> 6;
        int slot = atomicAdd(&lofs[b], 1);
        stag[slot] = make_int2((cc[k] & 0xFFFF) | ((row & 63) << 16) | (b << 22),
                               __float_as_int(vv[k]));
    }
    __syncthreads();
    for (int i = tid; i < cnt; i += 512) {
        int2 t = stag[i];
        unsigned b2 = ((unsigned)t.x) >> 22;
        int start = b2 ? lofs[b2 - 1] : 0;
        csr[gbase[b2] + (i - start)] = t;
    }
}

// ---------------------------------------------------------------------------
// Within-bucket counting sort by row (in place) + emit per-row rowptr.
// ---------------------------------------------------------------------------
__global__ __launch_bounds__(256) void rowsort_kernel(
    int2* __restrict__ csr, const int* __restrict__ gstart,
    int* __restrict__ rowptr)
{
    __shared__ int2 stag[RSCAP];
    __shared__ int cnt[64];
    __shared__ int ofs[64];
    int blk = blockIdx.x;
    int r   = blockIdx.y;
    int b   = r * NB + blk;
    int s = gstart[b], e = gstart[b + 1];
    int cntE = e - s; if (cntE > RSCAP) cntE = RSCAP;
    int tid = threadIdx.x;
    if (tid < 64) cnt[tid] = 0;
    __syncthreads();

    int2 ed[RSCAP / 256];
    #pragma unroll
    for (int j = 0; j < RSCAP / 256; ++j) {
        int i = tid + j * 256;
        if (i < cntE) {
            ed[j] = csr[s + i];
            atomicAdd(&cnt[(ed[j].x >> 16) & 63], 1);
        }
    }
    __syncthreads();
    if (tid < 64) {
        int c = cnt[tid];
        int inc = c;
        #pragma unroll
        for (int off = 1; off < 64; off <<= 1) {
            int u = __shfl_up(inc, off);
            if (tid >= off) inc += u;
        }
        ofs[tid] = inc - c;
        int n = blk * 64 + tid;
        if (n < NN) rowptr[(size_t)r * NN + n] = s + inc - c;
        if (b == NBUCK - 1 && tid == 0)
            rowptr[(size_t)NR * NN] = gstart[NBUCK];
    }
    __syncthreads();
    #pragma unroll
    for (int j = 0; j < RSCAP / 256; ++j) {
        int i = tid + j * 256;
        if (i < cntE) {
            int rl = (ed[j].x >> 16) & 63;
            int slot = atomicAdd(&ofs[rl], 1);
            stag[slot] = ed[j];
        }
    }
    __syncthreads();
    for (int i = tid; i < cntE; i += 256) csr[s + i] = stag[i];
}

// ---------------------------------------------------------------------------
// Fused SpMM v3: metadata-in-register + 2-stage software pipeline.
// ---------------------------------------------------------------------------
struct Stage {
    float    v[NR][2];
    uint32_t u[NR][2];
};

__device__ __forceinline__ void stage_issue(
    int k, const int* deg, const int* colv, const float* valv,
    const uint32_t* __restrict__ xw32, int half, int l2, Stage& st)
{
    #pragma unroll
    for (int r = 0; r < NR; ++r) {
        if (k < deg[r]) {                      // wave-uniform
            #pragma unroll
            for (int sub = 0; sub < 2; ++sub) {
                int e = k + 2 * sub + half;
                bool valid = e < deg[r];
                int ec = valid ? e : 0;
                int col = __shfl(colv[r], ec);
                float v = __shfl(valv[r], ec);
                st.v[r][sub] = valid ? v : 0.f;
                st.u[r][sub] = xw32[(((size_t)r * NN + col) << 5) + l2];
            }
        } else {
            #pragma unroll
            for (int sub = 0; sub < 2; ++sub) {
                st.v[r][sub] = 0.f;
                st.u[r][sub] = 0u;             // avoid 0*garbage NaN
            }
        }
    }
}

__device__ __forceinline__ void stage_consume(
    const Stage& st, float* a0, float* a1)
{
    #pragma unroll
    for (int r = 0; r < NR; ++r) {
        #pragma unroll
        for (int sub = 0; sub < 2; ++sub) {
            a0[r] = fmaf(st.v[r][sub],
                         __uint_as_float(st.u[r][sub] << 16), a0[r]);
            a1[r] = fmaf(st.v[r][sub],
                         __uint_as_float(st.u[r][sub] & 0xFFFF0000u), a1[r]);
        }
    }
}

__global__ __launch_bounds__(256) void spmm_fused_kernel(
    const uint32_t* __restrict__ xw32, const int2* __restrict__ csr,
    const int* __restrict__ rowptr, const float* __restrict__ bias,
    float* __restrict__ out)
{
    int n = __builtin_amdgcn_readfirstlane(
        (int)((blockIdx.x * 256 + threadIdx.x) >> 6));
    int lane = threadIdx.x & 63;
    int half = lane >> 5, l2 = lane & 31;
    if (n >= NN) return;

    int deg[NR]; int colv[NR]; float valv[NR];
    int sbeg[NR], send[NR];
    int maxdeg = 0;
    #pragma unroll
    for (int r = 0; r < NR; ++r) {
        sbeg[r] = rowptr[(size_t)r * NN + n];
        send[r] = rowptr[(size_t)r * NN + n + 1];
        int d = send[r] - sbeg[r];
        if (d > 64) d = 64;
        deg[r] = d;
        int2 cv = (lane < d) ? csr[sbeg[r] + lane] : make_int2(0, 0);
        colv[r] = cv.x & 0xFFFF;
        valv[r] = __int_as_float(cv.y);
        maxdeg = max(maxdeg, d);
    }

    float a0[NR] = {0.f,0.f,0.f,0.f};
    float a1[NR] = {0.f,0.f,0.f,0.f};

    Stage A, B;
    stage_issue(0, deg, colv, valv, xw32, half, l2, A);
    for (int k = 0; k < maxdeg; k += 8) {
        stage_issue(k + 4, deg, colv, valv, xw32, half, l2, B);
        stage_consume(A, a0, a1);
        stage_issue(k + 8, deg, colv, valv, xw32, half, l2, A);
        stage_consume(B, a0, a1);
    }

    // rare tail: deg > 64 (broadcast loop; half 0 accumulates only)
    #pragma unroll
    for (int r = 0; r < NR; ++r) {
        for (int i = sbeg[r] + 64; i < send[r]; ++i) {   // ~never taken
            int2 cv = csr[i];
            float v = (half == 0) ? __int_as_float(cv.y) : 0.f;
            int col = cv.x & 0xFFFF;
            uint32_t u = xw32[(((size_t)r * NN + col) << 5) + l2];
            a0[r] = fmaf(v, __uint_as_float(u << 16), a0[r]);
            a1[r] = fmaf(v, __uint_as_float(u & 0xFFFF0000u), a1[r]);
        }
    }

    float t0 = 0.f, t1 = 0.f;
    #pragma unroll
    for (int r = 0; r < NR; ++r) {
        a0[r] += __shfl_xor(a0[r], 32);
        a1[r] += __shfl_xor(a1[r], 32);
        float2 br = *(const float2*)&bias[r * DO + 2 * l2];
        t0 += fmaxf(a0[r] + br.x, 0.f);
        t1 += fmaxf(a1[r] + br.y, 0.f);
    }
    float s2 = t0 * t0 + t1 * t1;
    #pragma unroll
    for (int off = 16; off >= 1; off >>= 1) s2 += __shfl_xor(s2, off);
    float inv = 1.0f / fmaxf(sqrtf(s2), 1e-12f);
    if (half == 0) {
        float2 o = make_float2(t0 * inv, t1 * inv);
        *(float2*)&out[(size_t)n * DO + 2 * l2] = o;
    }
}

// ---------------------------------------------------------------------------
// Fallback path (small ws): R1 atomic-scatter pipeline.
// ---------------------------------------------------------------------------
__global__ __launch_bounds__(256) void scatter_kernel(
    const __hip_bfloat16* __restrict__ xwb, const float* __restrict__ vals,
    const int* __restrict__ rows, const int* __restrict__ cols,
    float* __restrict__ agg)
{
    const int nPairs = NE / 2;
    int gwave  = (blockIdx.x * 256 + threadIdx.x) >> 6;
    int half   = (threadIdx.x >> 5) & 1;
    int l32    = threadIdx.x & 31;
    int stride = gridDim.x * 4;
    const uint16_t* xw16 = reinterpret_cast<const uint16_t*>(xwb);
    for (int p = gwave; p < nPairs; p += stride) {
        int e = 2 * p + half;
        int row = rows[e]; int col = cols[e]; float v = vals[e];
        uint32_t packed = *reinterpret_cast<const uint32_t*>(
            xw16 + ((size_t)col << 6) + 2 * l32);
        float f0 = __uint_as_float(packed << 16);
        float f1 = __uint_as_float(packed & 0xFFFF0000u);
        float* dst = agg + ((size_t)row << 6) + 2 * l32;
        atomicAdd(dst,     v * f0);
        atomicAdd(dst + 1, v * f1);
    }
}

__global__ __launch_bounds__(256) void accum_kernel(
    float* __restrict__ agg, const float* __restrict__ b,
    float* __restrict__ out, int first)
{
    int i = blockIdx.x * 256 + threadIdx.x;
    if (i >= NN * DO) return;
    float v = agg[i] + b[i & (DO - 1)];
    agg[i] = 0.f;
    v = fmaxf(v, 0.f);
    out[i] = first ? v : (out[i] + v);
}

__global__ __launch_bounds__(256) void norm_kernel(float* __restrict__ out)
{
    int n = (blockIdx.x * 256 + threadIdx.x) >> 6;
    int lane = threadIdx.x & 63;
    if (n >= NN) return;
    size_t idx = (size_t)n * DO + lane;
    float t = out[idx];
    float s = t * t;
    #pragma unroll
    for (int off = 32; off >= 1; off >>= 1) s += __shfl_xor(s, off);
    out[idx] = t / fmaxf(sqrtf(s), 1e-12f);
}

extern "C" void kernel_launch(void* const* d_in, const int* in_sizes, int n_in,
                              void* d_out, int out_size, void* d_ws, size_t ws_size,
                              hipStream_t stream)
{
    const float* x    = (const float*)d_in[0];
    const float* W    = (const float*)d_in[1];
    const float* b    = (const float*)d_in[2];
    const float* vals = (const float*)d_in[3];
    const int*   rows = (const int*)d_in[4];
    const int*   cols = (const int*)d_in[5];
    float* out = (float*)d_out;
    char* ws = (char*)d_ws;

    // ws: xwb 25.6MB | csr 25.6MB | rowptr 3.2MB | gtot | gstart | gcur
    const size_t O_XW = 0;
    const size_t O_CS = O_XW + (size_t)NR * NN * DO * 2;
    const size_t O_RP = O_CS + (size_t)NR * NE * 8;
    const size_t O_GT = O_RP + ((size_t)NR * NN + 4) * 4;
    const size_t O_GS = O_GT + (size_t)NBUCK * 4;
    const size_t O_GC = O_GS + (size_t)(NBUCK + 1) * 4;
    const size_t NEED = O_GC + (size_t)NBUCK * 4;

    if (ws_size >= NEED) {
        __hip_bfloat16* xwb = (__hip_bfloat16*)(ws + O_XW);
        int2* csr   = (int2*)(ws + O_CS);
        int* rowptr = (int*)(ws + O_RP);
        int* gtot   = (int*)(ws + O_GT);
        int* gstart = (int*)(ws + O_GS);
        int* gcur   = (int*)(ws + O_GC);

        hipMemsetAsync(gtot, 0, (size_t)NBUCK * 4, stream);
        gemm4_kernel<<<dim3(NB), dim3(256), 0, stream>>>(x, W, xwb);
        bhist_kernel<<<dim3(32, NR), dim3(256), 0, stream>>>(rows, gtot);
        bases_kernel<<<dim3(1), dim3(512), 0, stream>>>(gtot, gstart, gcur);
        place_kernel<<<dim3(PWG, NR), dim3(512), 0, stream>>>(rows, cols, vals, gcur, csr);
        rowsort_kernel<<<dim3(NB, NR), dim3(256), 0, stream>>>(csr, gstart, rowptr);
        spmm_fused_kernel<<<dim3((NN * 64 + 255) / 256), dim3(256), 0, stream>>>(
            (const uint32_t*)xwb, csr, rowptr, b, out);
    } else {
        // sequential atomic-scatter fallback (19.2MB)
        __hip_bfloat16* xwb = (__hip_bfloat16*)ws;
        float* agg = (float*)(ws + (size_t)NN * DO * 2);
        hipMemsetAsync(agg, 0, (size_t)NN * DO * 4, stream);
        for (int r = 0; r < NR; ++r) {
            gemm_kernel<<<dim3((NN + 31) / 32), dim3(256), 0, stream>>>(
                x, W + (size_t)r * DI * DO, xwb);
            scatter_kernel<<<dim3(2048), dim3(256), 0, stream>>>(
                xwb, vals + (size_t)r * NE, rows + (size_t)r * NE,
                cols + (size_t)r * NE, agg);
            accum_kernel<<<dim3((NN * DO + 255) / 256), dim3(256), 0, stream>>>(
                agg, b + (size_t)r * DO, out, r == 0);
        }
        norm_kernel<<<dim3((NN * DO + 255) / 256), dim3(256), 0, stream>>>(out);
    }
}